// Round 1
// baseline (264.882 us; speedup 1.0000x reference)
//
#include <hip/hip_runtime.h>

// CTC loss forward: B=1024 seqs, T=1024 steps, C=96 classes, L=32 labels,
// S=2L+1=65 extended states, blank = C-1 = 95.
// One block (4 waves) per batch element. 3 producer waves compute per-step
// log-softmax + gather of extended-label log-probs into an LDS ring; 1
// consumer wave runs the alpha recursion (lane = state, state 64 uniform).

#define NB 1024
#define NT 1024
#define NC 96
#define NL 32
#define BLANKC 95
#define NEGF (-1e30f)
#define CHUNK 32
#define NCHUNK (NT / CHUNK)
#define SLOTF 66                 // 65 lp values + 1 pad (odd stride, conflict-free)
#define RINGSLOTS 64             // 2 chunks double-buffered

__device__ __forceinline__ float wmax64(float v) {
  v = fmaxf(v, __shfl_xor(v, 32));
  v = fmaxf(v, __shfl_xor(v, 16));
  v = fmaxf(v, __shfl_xor(v, 8));
  v = fmaxf(v, __shfl_xor(v, 4));
  v = fmaxf(v, __shfl_xor(v, 2));
  v = fmaxf(v, __shfl_xor(v, 1));
  return v;
}
__device__ __forceinline__ float wsum64(float v) {
  v += __shfl_xor(v, 32);
  v += __shfl_xor(v, 16);
  v += __shfl_xor(v, 8);
  v += __shfl_xor(v, 4);
  v += __shfl_xor(v, 2);
  v += __shfl_xor(v, 1);
  return v;
}

__global__ __launch_bounds__(256) void ctc_fused(const int* __restrict__ yt,
                                                 const float* __restrict__ yp,
                                                 float* __restrict__ out) {
  __shared__ float ring[RINGSLOTS * SLOTF];

  const int b = blockIdx.x;
  const int wid = threadIdx.x >> 6;
  const int lane = threadIdx.x & 63;

  // extended-label class for state s=lane, and skip-transition mask
  const int* lab = yt + b * NL;
  int extc = BLANKC;
  bool skipf = false;
  if (lane & 1) {
    int j = (lane - 1) >> 1;
    extc = lab[j];
    if (j > 0) skipf = (extc != lab[j - 1]);
  }

  const float* __restrict__ xrow = yp + (size_t)b * NT * NC;

  // scramble consumer wave across SIMDs (wave i of a block lands on SIMD i%4)
  const int cw = b & 3;
  const bool is_cons = (wid == cw);
  const int pr = ((wid - cw + 4) & 3) - 1;  // producer rank 0..2 (consumer: -1)

  // ---- producer: fill CHUNK time steps starting at t0 (this wave's share) ----
  auto produce_chunk = [&](int t0) {
    float v0[11], v1[11];
#pragma unroll
    for (int j = 0; j < 11; ++j) {
      const int si = pr + 3 * j;
      if (si < CHUNK) {
        const float* row = xrow + (size_t)(t0 + si) * NC;
        v0[j] = row[lane];
        v1[j] = (lane < 32) ? row[64 + lane] : -INFINITY;
      }
    }
#pragma unroll
    for (int j = 0; j < 11; ++j) {
      const int si = pr + 3 * j;
      if (si < CHUNK) {
        const float m = wmax64(fmaxf(v0[j], v1[j]));
        const float Z = wsum64(__expf(v0[j] - m) + __expf(v1[j] - m));
        const float logZ = m + __logf(Z);
        const float g0 = __shfl(v0[j], extc);        // extc < 64 path
        const float g1 = __shfl(v1[j], extc - 64);   // extc >= 64 path
        const float lp = ((extc < 64) ? g0 : g1) - logZ;
        const int slot = ((t0 + si) & (RINGSLOTS - 1)) * SLOTF;
        ring[slot + lane] = lp;
        if (lane == 0) ring[slot + 64] = lp;  // state 64 is blank == state 0's class
      }
    }
  };

  float alpha = NEGF;  // alpha[state = lane]
  float a64 = NEGF;    // alpha[64], wave-uniform

  if (!is_cons) produce_chunk(0);
  __syncthreads();

  for (int c = 0; c < NCHUNK; ++c) {
    if (is_cons) {
#pragma unroll
      for (int tt = 0; tt < CHUNK; ++tt) {
        const int t = c * CHUNK + tt;
        const int slot = (t & (RINGSLOTS - 1)) * SLOTF;
        const float lp = ring[slot + lane];
        const float lp64 = ring[slot + 64];
        if (tt == 0 && c == 0) {
          // t = 0 init: only states 0,1 start
          alpha = (lane < 2) ? lp : NEGF;
          a64 = NEGF;
        } else {
          float ap = __shfl_up(alpha, 1);
          ap = (lane == 0) ? NEGF : ap;
          float as = __shfl_up(alpha, 2);
          as = skipf ? as : NEGF;
          const float a63 = __shfl(alpha, 63);  // old alpha[63] for state 64
          const float mm = fmaxf(fmaxf(alpha, ap), as);
          const float sm = __expf(alpha - mm) + __expf(ap - mm) + __expf(as - mm);
          alpha = mm + __logf(sm) + lp;
          const float m2 = fmaxf(a64, a63);
          a64 = m2 + __logf(__expf(a64 - m2) + __expf(a63 - m2)) + lp64;
        }
      }
    } else if (c + 1 < NCHUNK) {
      produce_chunk((c + 1) * CHUNK);
    }
    __syncthreads();
  }

  if (is_cons) {
    const float aS2 = __shfl(alpha, 63);
    const float mF = fmaxf(a64, aS2);
    const float loss = -(mF + __logf(__expf(a64 - mF) + __expf(aS2 - mF)));
    if (lane == 0) out[b] = loss;
  }
}

extern "C" void kernel_launch(void* const* d_in, const int* in_sizes, int n_in,
                              void* d_out, int out_size, void* d_ws, size_t ws_size,
                              hipStream_t stream) {
  const int* yt = (const int*)d_in[0];     // y_true: [B, L] int32
  const float* yp = (const float*)d_in[1]; // y_pred: [B, T, C] float32
  float* out = (float*)d_out;              // loss: [B, 1] float32
  hipLaunchKernelGGL(ctc_fused, dim3(NB), dim3(256), 0, stream, yt, yp, out);
}

// Round 2
// 126.548 us; speedup vs baseline: 2.0931x; 2.0931x over previous
//
#include <hip/hip_runtime.h>

// CTC loss forward: B=1024, T=1024, C=96, L=32, S=65 states, blank=95.
// One block (4 waves) per batch element: 3 producer waves compute per-row
// log-softmax (log2 domain) and store full normalized rows into an LDS ring;
// 1 consumer wave runs the alpha recursion (lane = state-1; state 0 is a
// wave-uniform running sum since it only has a self-transition).

#define NB 1024
#define NT 1024
#define NC 96
#define NL 32
#define NEGF (-1e30f)
#define CHUNK 32
#define NCHUNK (NT / CHUNK)
#define SLOTF 97                 // 96 classes + 1 pad (odd stride rotates banks)
#define RINGSLOTS 64             // 2 chunks double-buffered
#define LOG2E 1.4426950408889634f
#define LN2   0.69314718055994531f

__device__ __forceinline__ float fexp2(float x) { return __builtin_amdgcn_exp2f(x); }
__device__ __forceinline__ float flog2(float x) { return __builtin_amdgcn_logf(x); }

__global__ __launch_bounds__(256) void ctc_fused(const int* __restrict__ yt,
                                                 const float* __restrict__ yp,
                                                 float* __restrict__ out) {
  __shared__ float ring[RINGSLOTS * SLOTF];

  const int b = blockIdx.x;
  const int wid = threadIdx.x >> 6;
  const int lane = threadIdx.x & 63;

  const float* __restrict__ xrow = yp + (size_t)b * NT * NC;

  // scramble consumer wave across SIMDs (wave i of a block lands on SIMD i%4)
  const int cw = b & 3;
  const bool is_cons = (wid == cw);
  const int pr = ((wid - cw + 4) & 3) - 1;  // producer rank 0..2 (consumer: -1)

  // consumer lane s <-> state s+1. Odd states (labels) are even lanes.
  int extc = 95;
  bool skipf = false;
  if (is_cons) {
    const int* lab = yt + b * NL;
    if ((lane & 1) == 0) {
      const int j = lane >> 1;       // state = 2j+1 = label j
      extc = lab[j];
      skipf = (j > 0) && (extc != lab[j - 1]);
    }
  }

  // ---- producer: 2 rows per wave pass, 3 classes per lane, 16 pairs/chunk ----
  auto produce_chunk = [&](int t0) {
    const int rsel = lane >> 5;      // 0/1: which row of the pair
    const int l32 = lane & 31;
    float u0[6], u1[6], u2[6];
#pragma unroll
    for (int jj = 0; jj < 6; ++jj) {
      const int p = pr + 3 * jj;
      if (p < 16) {
        const float* rp = xrow + (size_t)(t0 + 2 * p + rsel) * NC + l32;
        u0[jj] = rp[0] * LOG2E;
        u1[jj] = rp[32] * LOG2E;
        u2[jj] = rp[64] * LOG2E;
      }
    }
#pragma unroll
    for (int jj = 0; jj < 6; ++jj) {
      const int p = pr + 3 * jj;
      if (p < 16) {
        float m = fmaxf(fmaxf(u0[jj], u1[jj]), u2[jj]);
        m = fmaxf(m, __shfl_xor(m, 1));
        m = fmaxf(m, __shfl_xor(m, 2));
        m = fmaxf(m, __shfl_xor(m, 4));
        m = fmaxf(m, __shfl_xor(m, 8));
        m = fmaxf(m, __shfl_xor(m, 16));
        float z = fexp2(u0[jj] - m) + fexp2(u1[jj] - m) + fexp2(u2[jj] - m);
        z += __shfl_xor(z, 1);
        z += __shfl_xor(z, 2);
        z += __shfl_xor(z, 4);
        z += __shfl_xor(z, 8);
        z += __shfl_xor(z, 16);
        const float lz = m + flog2(z);
        const int base = ((t0 + 2 * p + rsel) & (RINGSLOTS - 1)) * SLOTF + l32;
        ring[base] = u0[jj] - lz;
        ring[base + 32] = u1[jj] - lz;
        ring[base + 64] = u2[jj] - lz;
      }
    }
  };

  float alpha = NEGF;  // alpha[state = lane+1], log2 units
  float a0 = NEGF;     // alpha[state 0], wave-replicated running sum

  if (!is_cons) produce_chunk(0);
  __syncthreads();

  for (int c = 0; c < NCHUNK; ++c) {
    if (is_cons) {
#pragma unroll
      for (int tt = 0; tt < CHUNK; ++tt) {
        const int t = c * CHUNK + tt;
        const int base = (t & (RINGSLOTS - 1)) * SLOTF;
        const float lp = ring[base + extc];   // my state's class (gather)
        const float lpb = ring[base + 95];    // blank (uniform addr, broadcast)
        if (c == 0 && tt == 0) {
          a0 = lpb;                            // state 0
          alpha = (lane == 0) ? lp : NEGF;     // state 1 = label 0
        } else {
          float ap = __shfl_up(alpha, 1);
          ap = (lane == 0) ? a0 : ap;          // state 1's prev is state 0
          float as = __shfl_up(alpha, 2);
          as = skipf ? as : NEGF;
          const float mm = fmaxf(fmaxf(alpha, ap), as);
          const float sm = fexp2(alpha - mm) + fexp2(ap - mm) + fexp2(as - mm);
          alpha = mm + flog2(sm) + lp;
          a0 += lpb;
        }
      }
    } else if (c + 1 < NCHUNK) {
      produce_chunk((c + 1) * CHUNK);
    }
    __syncthreads();
  }

  if (is_cons) {
    const float aS1 = __shfl(alpha, 63);  // state 64 (last blank)
    const float aS2 = __shfl(alpha, 62);  // state 63 (last label)
    if (lane == 0) {
      const float mF = fmaxf(aS1, aS2);
      const float r = mF + flog2(fexp2(aS1 - mF) + fexp2(aS2 - mF));
      out[b] = -r * LN2;
    }
  }
}

extern "C" void kernel_launch(void* const* d_in, const int* in_sizes, int n_in,
                              void* d_out, int out_size, void* d_ws, size_t ws_size,
                              hipStream_t stream) {
  const int* yt = (const int*)d_in[0];     // y_true: [B, L]
  const float* yp = (const float*)d_in[1]; // y_pred: [B, T, C] float32
  float* out = (float*)d_out;              // loss: [B, 1] float32
  hipLaunchKernelGGL(ctc_fused, dim3(NB), dim3(256), 0, stream, yt, yp, out);
}